// Round 9
// baseline (493.220 us; speedup 1.0000x reference)
//
#include <hip/hip_runtime.h>
#include <hip/hip_bf16.h>

typedef __attribute__((ext_vector_type(8)))  short short8;
typedef __attribute__((ext_vector_type(16))) float f32x16;

#define LOG2E 1.44269504088896f
#define CS (0.125f * LOG2E)

static __device__ __forceinline__ short f2b(float f) {
  union { __hip_bfloat16 h; short s; } u; u.h = __float2bfloat16(f); return u.s;
}
static __device__ __forceinline__ f32x16 zf16() {
  f32x16 z;
#pragma unroll
  for (int i = 0; i < 16; ++i) z[i] = 0.f;
  return z;
}
static __device__ __forceinline__ f32x16 mfma32(short8 a, short8 b, f32x16 c) {
  return __builtin_amdgcn_mfma_f32_32x32x16_bf16(a, b, c, 0, 0, 0);
}

// ---------------- kernel 0: convert + transposes ----------------
__global__ void k_convert(const float* __restrict__ x, const float* __restrict__ wqkv,
                          const float* __restrict__ wout,
                          short* __restrict__ xb, short* __restrict__ wqkvT,
                          short* __restrict__ woutT) {
  const int NX = 2 * 2048 * 512;
  const int NW = 512 * 1536;
  const int NO = 512 * 512;
  int i = blockIdx.x * 256 + threadIdx.x;
  if (i < NX) {
    xb[i] = f2b(x[i]);
  } else if (i < NX + NW) {
    int o = i - NX; int n = o >> 9; int k = o & 511;
    wqkvT[o] = f2b(wqkv[k * 1536 + n]);
  } else if (i < NX + NW + NO) {
    int o = i - NX - NW; int n = o >> 9; int k = o & 511;
    woutT[o] = f2b(wout[k * 512 + n]);
  }
}

// ---------------- kernel 0b: x.sum(axis=1) into d_out ----------------
__global__ void k_xsum(const float* __restrict__ x, float* __restrict__ outacc) {
  int blk = blockIdx.x;            // 32
  int b = blk >> 4, ch = blk & 15;
  int t = threadIdx.x;             // 256
  int f = t * 2;
  float s0 = 0.f, s1 = 0.f;
  const float* base = x + ((size_t)b * 2048 + (size_t)ch * 128) * 512;
  for (int r = 0; r < 128; ++r) {
    float2 v = *(const float2*)(base + (size_t)r * 512 + f);
    s0 += v.x; s1 += v.y;
  }
  atomicAdd(&outacc[b * 512 + f], s0);
  atomicAdd(&outacc[b * 512 + f + 1], s1);
}

// ---------------- kernel 1: qkv GEMM ----------------
__launch_bounds__(256)
__global__ void k_qkv(const short* __restrict__ xb, const short* __restrict__ wqkvT,
                      short* __restrict__ qg, short* __restrict__ kg,
                      short* __restrict__ vtmp) {
  __shared__ __align__(16) short As[128 * 64];
  __shared__ __align__(16) short Bs[128 * 64];
  int bx = blockIdx.x & 31;
  int by = blockIdx.x >> 5;
  int row0 = bx << 7, col0 = by << 7;
  int t = threadIdx.x, w = t >> 6, l = t & 63, li = l & 31, hi = l >> 5;
  int wr = w >> 1, wc = w & 1;
  f32x16 acc[2][2];
#pragma unroll
  for (int mi = 0; mi < 2; ++mi)
#pragma unroll
    for (int ni = 0; ni < 2; ++ni) acc[mi][ni] = zf16();

  for (int k0 = 0; k0 < 512; k0 += 64) {
    __syncthreads();
#pragma unroll
    for (int it = 0; it < 4; ++it) {
      int idx = t + it * 256;
      int r = idx >> 3, pc = idx & 7;
      int4 va = *(const int4*)(xb + (size_t)(row0 + r) * 512 + k0 + pc * 8);
      int dsto = (r * 128 + pc * 16) ^ ((r & 7) << 4);
      *(int4*)((char*)As + dsto) = va;
      int4 vb = *(const int4*)(wqkvT + (size_t)(col0 + r) * 512 + k0 + pc * 8);
      *(int4*)((char*)Bs + dsto) = vb;
    }
    __syncthreads();
#pragma unroll
    for (int kk = 0; kk < 4; ++kk) {
      short8 af[2], bfv[2];
#pragma unroll
      for (int mi = 0; mi < 2; ++mi) {
        int row = wr * 64 + mi * 32 + li;
        int byteo = (row * 128 + (kk * 2 + hi) * 16) ^ ((row & 7) << 4);
        af[mi] = *(const short8*)((char*)As + byteo);
      }
#pragma unroll
      for (int ni = 0; ni < 2; ++ni) {
        int col = wc * 64 + ni * 32 + li;
        int byteo = (col * 128 + (kk * 2 + hi) * 16) ^ ((col & 7) << 4);
        bfv[ni] = *(const short8*)((char*)Bs + byteo);
      }
#pragma unroll
      for (int mi = 0; mi < 2; ++mi)
#pragma unroll
        for (int ni = 0; ni < 2; ++ni)
          acc[mi][ni] = mfma32(af[mi], bfv[ni], acc[mi][ni]);
    }
  }
#pragma unroll
  for (int mi = 0; mi < 2; ++mi)
#pragma unroll
    for (int ni = 0; ni < 2; ++ni) {
      int colb = col0 + wc * 64 + ni * 32 + li;
      int sect = colb >> 9, rem = colb & 511, h = rem >> 6, d = rem & 63;
      short* dst = sect == 0 ? qg : (sect == 1 ? kg : vtmp);
#pragma unroll
      for (int r = 0; r < 16; ++r) {
        int row = row0 + wr * 64 + mi * 32 + ((r & 3) + ((r >> 2) << 3) + (hi << 2));
        int b = row >> 11, nn = row & 2047;
        dst[(((size_t)(b * 8 + h) * 2048 + nn) << 6) + d] = f2b(acc[mi][ni][r]);
      }
    }
}

// ---------------- kernel 1b: transpose v -> vt[b][h][d][n] ----------------
__global__ void k_vt(const short* __restrict__ vtmp, short* __restrict__ vt) {
  __shared__ __align__(16) short tile[64 * 72];
  int blk = blockIdx.x;        // 512
  int bh = blk >> 5;
  int n0 = (blk & 31) << 6;
  int t = threadIdx.x;         // 256
#pragma unroll
  for (int it = 0; it < 2; ++it) {
    int idx = (t + it * 256) * 8;
    int r = idx >> 6, c = idx & 63;
    int4 v = *(const int4*)(vtmp + ((size_t)bh * 2048 + n0 + r) * 64 + c);
    *(int4*)(&tile[r * 72 + c]) = v;
  }
  __syncthreads();
#pragma unroll
  for (int it = 0; it < 2; ++it) {
    int idx = (t + it * 256) * 8;
    int d = idx >> 6, nn = idx & 63;
    short8 o;
#pragma unroll
    for (int j = 0; j < 8; ++j) o[j] = tile[(nn + j) * 72 + d];
    *(short8*)(vt + ((size_t)bh * 64 + d) * 2048 + n0 + nn) = o;
  }
}

// ---------------- kernel 2a: softmax stats, 4-wave j-split ----------------
__launch_bounds__(256)
__global__ void k_stats(const short* __restrict__ qg, const short* __restrict__ kg,
                        float* __restrict__ ml) {
  __shared__ float red[4][32][2];
  int t = threadIdx.x, w = t >> 6, l = t & 63, li = l & 31, hi = l >> 5;
  int blk = blockIdx.x;                  // 1024 = b*h*it
  int b = blk >> 9, rem = blk & 511, h = rem >> 6, it = rem & 63;
  size_t bh = (size_t)(b * 8 + h) * 2048;
  int i = it * 32 + li;
  short8 q4[4];
#pragma unroll
  for (int kk = 0; kk < 4; ++kk)
    q4[kk] = *(const short8*)(qg + (bh + i) * 64 + kk * 16 + hi * 8);
  float m2 = -1e30f, ls = 0.f;
  for (int jt = w * 16; jt < w * 16 + 16; ++jt) {
    f32x16 s = zf16();
#pragma unroll
    for (int kk = 0; kk < 4; ++kk) {
      short8 kf = *(const short8*)(kg + (bh + jt * 32 + li) * 64 + kk * 16 + hi * 8);
      s = mfma32(kf, q4[kk], s);
    }
    float sv[16];
    float tm = -1e30f;
#pragma unroll
    for (int r = 0; r < 16; ++r) { sv[r] = s[r] * CS; tm = fmaxf(tm, sv[r]); }
    float mn = fmaxf(m2, tm);
    float acc = 0.f;
#pragma unroll
    for (int r = 0; r < 16; ++r) acc += exp2f(sv[r] - mn);
    ls = ls * exp2f(m2 - mn) + acc;
    m2 = mn;
  }
  // merge hi halves within wave
  float om = __shfl_xor(m2, 32, 64);
  float ol = __shfl_xor(ls, 32, 64);
  float mf = fmaxf(m2, om);
  float lf = ls * exp2f(m2 - mf) + ol * exp2f(om - mf);
  if (hi == 0) { red[w][li][0] = mf; red[w][li][1] = lf; }
  __syncthreads();
  if (t < 32) {
    float m = red[0][t][0], s = red[0][t][1];
#pragma unroll
    for (int ww = 1; ww < 4; ++ww) {
      float m1 = red[ww][t][0], s1 = red[ww][t][1];
      float mn = fmaxf(m, m1);
      s = s * exp2f(m - mn) + s1 * exp2f(m1 - mn);
      m = mn;
    }
    *(float2*)(ml + (bh + it * 32 + t) * 2) = make_float2(m, s);
  }
}

// ---------------- kernel 2b: fused attn (MFMA head-mix) ----------------
// p_lds: P as bf16, [c = i*32+j][h], byte = (c*16 + 2h) ^ (((c>>5)&7)<<4)
// mix via mfma: D[g][c] = sum_h mixT[g][h] * P[h][c]  (K=16, upper 8 zero)
__launch_bounds__(512)
__global__ void k_attn(const short* __restrict__ qg, const short* __restrict__ kg,
                       const short* __restrict__ vt, const float* __restrict__ ml,
                       const float* __restrict__ mixg, const float* __restrict__ lnhg,
                       const float* __restrict__ lnhb, float* __restrict__ attn,
                       float* __restrict__ oh) {
  __shared__ __align__(16) short p_lds[1024 * 8];      // 16 KB
  __shared__ __align__(16) short a_lds[8 * 32 * 40];   // 20.5 KB
  int t = threadIdx.x;
  int w = t >> 6, l = t & 63, li = l & 31, hi = l >> 5;
  int blk = blockIdx.x;           // 512
  int jg = blk & 3, itile = (blk >> 2) & 63, b = blk >> 8;
  int i0 = itile * 32;
  int h = w;
  size_t bh = (size_t)(b * 8 + h) * 2048;

  // A-frag for the mix MFMA: row g = li (valid g<8), k = hi*8+e (valid k<8)
  short8 mixA;
#pragma unroll
  for (int e = 0; e < 8; ++e)
    mixA[e] = (hi == 0 && li < 8) ? f2b(mixg[e * 8 + li]) : (short)0;
  float lg4[4], lb4[4];
#pragma unroll
  for (int e = 0; e < 4; ++e) { lg4[e] = lnhg[4 * hi + e]; lb4[e] = lnhb[4 * hi + e]; }

  short8 q4[4];
#pragma unroll
  for (int kk = 0; kk < 4; ++kk)
    q4[kk] = *(const short8*)(qg + (bh + i0 + li) * 64 + kk * 16 + hi * 8);
  float2 mlv = *(const float2*)(ml + (bh + i0 + li) * 2);
  float c0 = -(mlv.x + __log2f(mlv.y));   // p = exp2(s*CS + c0)

  f32x16 oacc[2];
  oacc[0] = zf16(); oacc[1] = zf16();

  for (int jt = 0; jt < 16; ++jt) {
    int j0 = jg * 512 + jt * 32;
    // ---- QK^T: lane holds P[j=crow(r,hi)][i=li] ----
    f32x16 s = zf16();
#pragma unroll
    for (int kk = 0; kk < 4; ++kk) {
      short8 kf = *(const short8*)(kg + (bh + j0 + li) * 64 + kk * 16 + hi * 8);
      s = mfma32(kf, q4[kk], s);
    }
    // ---- exp2 -> bf16 -> p_lds[c][h] swizzled ----
#pragma unroll
    for (int r = 0; r < 16; ++r) {
      float p = exp2f(fmaf(s[r], CS, c0));
      int jr = (r & 3) + ((r >> 2) << 3) + (hi << 2);
      int c = li * 32 + jr;                     // c = i*32 + j  (i = li here)
      int byteo = (c * 16 + h * 2) ^ ((li & 7) << 4);
      *(short*)((char*)p_lds + byteo) = f2b(p);
    }
    __syncthreads();
    // ---- mix MFMA + head-LN; wave w handles col-chunks (i) = 4w..4w+3 ----
#pragma unroll
    for (int mm = 0; mm < 4; ++mm) {
      int m = w * 4 + mm;                       // = i
      short8 pB;
      if (hi == 0) {
        int byteo = (m * 512 + li * 16) ^ ((m & 7) << 4);
        pB = *(const short8*)((char*)p_lds + byteo);
      } else {
#pragma unroll
        for (int e = 0; e < 8; ++e) pB[e] = 0;
      }
      f32x16 macc = mfma32(mixA, pB, zf16());
      // macc[0..3] = rows g = 4*hi..4*hi+3 for col j = li
      float a4[4], o4[4];
#pragma unroll
      for (int e = 0; e < 4; ++e) { a4[e] = macc[e]; o4[e] = __shfl_xor(macc[e], 32, 64); }
      float mu = 0.f;
#pragma unroll
      for (int e = 0; e < 4; ++e) mu += a4[e] + o4[e];
      mu *= 0.125f;
      float var = 0.f;
#pragma unroll
      for (int e = 0; e < 4; ++e) {
        float d1 = a4[e] - mu, d2 = o4[e] - mu;
        var = fmaf(d1, d1, var); var = fmaf(d2, d2, var);
      }
      var *= 0.125f;
      float rs = rsqrtf(var + 1e-5f);
#pragma unroll
      for (int e = 0; e < 4; ++e) {
        float y = (a4[e] - mu) * rs * lg4[e] + lb4[e];
        int g = 4 * hi + e;
        attn[((size_t)(b * 8 + g) * 2048 + (size_t)(i0 + m)) * 2048 + j0 + li] = y;
        a_lds[(g * 32 + m) * 40 + li] = f2b(y);
      }
    }
    __syncthreads();
    // ---- PV ----
#pragma unroll
    for (int ks = 0; ks < 2; ++ks) {
      short8 af = *(const short8*)(&a_lds[(h * 32 + li) * 40 + ks * 16 + hi * 8]);
#pragma unroll
      for (int dt = 0; dt < 2; ++dt) {
        short8 vf = *(const short8*)(vt + ((size_t)(b * 8 + h) * 64 + dt * 32 + li) * 2048 + j0 + ks * 16 + hi * 8);
        oacc[dt] = mfma32(af, vf, oacc[dt]);
      }
    }
  }
  // partial oh per jg (no atomics); layout [jg][b][n][h*64+d]
  float* ohp = oh + (size_t)jg * (2 * 2048 * 512);
#pragma unroll
  for (int dt = 0; dt < 2; ++dt)
#pragma unroll
    for (int r = 0; r < 16; ++r) {
      int ri = (r & 3) + ((r >> 2) << 3) + (hi << 2);
      ohp[((size_t)(b * 2048 + i0 + ri)) * 512 + h * 64 + dt * 32 + li] = oacc[dt][r];
    }
}

// ---------------- kernel 3: epilogue GEMM + LN + reduce (32-row tiles) ----------------
__launch_bounds__(512)
__global__ void k_epi(const float* __restrict__ oh, const short* __restrict__ woutT,
                      const float* __restrict__ bo, const float* __restrict__ logv,
                      const float* __restrict__ lob, float* __restrict__ dout) {
  __shared__ __align__(16) short As[32 * 64];
  __shared__ float lnsum[32][8];
  __shared__ float lnsq[32][8];
  __shared__ float zsum[512];
  const size_t NPART = (size_t)2 * 2048 * 512;
  int t = threadIdx.x, w = t >> 6, l = t & 63, li = l & 31, hi = l >> 5;
  int m0 = blockIdx.x * 32;         // 128 blocks
  f32x16 acc[2];
  acc[0] = zf16(); acc[1] = zf16();

  for (int k0 = 0; k0 < 512; k0 += 64) {
    __syncthreads();
    {
      int r = t >> 4, c = (t & 15) * 4;
      size_t off = (size_t)(m0 + r) * 512 + k0 + c;
      float4 v = *(const float4*)(oh + off);
#pragma unroll
      for (int p = 1; p < 4; ++p) {
        float4 v2 = *(const float4*)(oh + p * NPART + off);
        v.x += v2.x; v.y += v2.y; v.z += v2.z; v.w += v2.w;
      }
      short o[4] = { f2b(v.x), f2b(v.y), f2b(v.z), f2b(v.w) };
      int byteo = (r * 128 + c * 2) ^ ((r & 7) << 4);
      *(int2*)((char*)As + byteo) = *(int2*)o;
    }
    __syncthreads();
#pragma unroll
    for (int kk = 0; kk < 4; ++kk) {
      int byteo = (li * 128 + (kk * 2 + hi) * 16) ^ ((li & 7) << 4);
      short8 af = *(const short8*)((char*)As + byteo);
#pragma unroll
      for (int ni = 0; ni < 2; ++ni) {
        int n = w * 64 + ni * 32 + li;
        short8 bfr = *(const short8*)(woutT + (size_t)n * 512 + k0 + kk * 16 + hi * 8);
        acc[ni] = mfma32(af, bfr, acc[ni]);
      }
    }
  }
  float bias[2], gg[2], b2[2];
#pragma unroll
  for (int ni = 0; ni < 2; ++ni) {
    int n = w * 64 + ni * 32 + li;
    bias[ni] = bo[n]; gg[ni] = logv[n]; b2[ni] = lob[n];
  }
#pragma unroll
  for (int ni = 0; ni < 2; ++ni)
#pragma unroll
    for (int r = 0; r < 16; ++r) acc[ni][r] += bias[ni];

#pragma unroll
  for (int r = 0; r < 16; ++r) {
    float s = acc[0][r] + acc[1][r];
    float q2 = fmaf(acc[0][r], acc[0][r], acc[1][r] * acc[1][r]);
    for (int d2 = 1; d2 < 32; d2 <<= 1) { s += __shfl_xor(s, d2); q2 += __shfl_xor(q2, d2); }
    int row = (r & 3) + ((r >> 2) << 3) + (hi << 2);
    if (li == 0) { lnsum[row][w] = s; lnsq[row][w] = q2; }
  }
  __syncthreads();
  if (t < 32) {
    float s = 0.f, q2 = 0.f;
#pragma unroll
    for (int ww = 0; ww < 8; ++ww) { s += lnsum[t][ww]; q2 += lnsq[t][ww]; }
    float m2 = s * (1.f / 512.f);
    float var = q2 * (1.f / 512.f) - m2 * m2;
    lnsum[t][0] = m2;
    lnsq[t][0] = rsqrtf(var + 1e-5f);
  }
  __syncthreads();
  float zc[2] = {0.f, 0.f};
#pragma unroll
  for (int r = 0; r < 16; ++r) {
    int row = (r & 3) + ((r >> 2) << 3) + (hi << 2);
    float m2 = lnsum[row][0], rs = lnsq[row][0];
#pragma unroll
    for (int ni = 0; ni < 2; ++ni)
      zc[ni] += (acc[ni][r] - m2) * rs * gg[ni] + b2[ni];
  }
#pragma unroll
  for (int ni = 0; ni < 2; ++ni) zc[ni] += __shfl_xor(zc[ni], 32);
  if (hi == 0) {
#pragma unroll
    for (int ni = 0; ni < 2; ++ni) zsum[w * 64 + ni * 32 + li] = zc[ni];
  }
  __syncthreads();
  int bsel = m0 >> 11;
  atomicAdd(&dout[bsel * 512 + t], zsum[t]);
}

// ---------------- launch ----------------
extern "C" void kernel_launch(void* const* d_in, const int* in_sizes, int n_in,
                              void* d_out, int out_size, void* d_ws, size_t ws_size,
                              hipStream_t stream) {
  const float* x    = (const float*)d_in[0];
  const float* wqkv = (const float*)d_in[1];
  const float* mixg = (const float*)d_in[2];
  const float* lnhg = (const float*)d_in[3];
  const float* lnhb = (const float*)d_in[4];
  const float* wout = (const float*)d_in[5];
  const float* bo   = (const float*)d_in[6];
  const float* logv = (const float*)d_in[7];
  const float* lob  = (const float*)d_in[8];
  float* dout = (float*)d_out;
  char* ws = (char*)d_ws;
  short* xb    = (short*)(ws + 0);
  short* wqkvT = (short*)(ws + 4194304);
  short* woutT = (short*)(ws + 5767168);
  short* qg    = (short*)(ws + 6291456);
  short* kg    = (short*)(ws + 10485760);
  short* vtmp  = (short*)(ws + 14680064);
  short* vt    = (short*)(ws + 18874368);
  float* ml    = (float*)(ws + 23068672);
  float* oh    = (float*)(ws + 23330816);   // 4 partials × 8 MB

  hipMemsetAsync(dout, 0, 1024 * sizeof(float), stream);

  k_convert<<<12288, 256, 0, stream>>>(x, wqkv, wout, xb, wqkvT, woutT);
  k_xsum<<<32, 256, 0, stream>>>(x, dout);
  k_qkv<<<384, 256, 0, stream>>>(xb, wqkvT, qg, kg, vtmp);
  k_vt<<<512, 256, 0, stream>>>(vtmp, vt);
  k_stats<<<1024, 256, 0, stream>>>(qg, kg, ml);
  k_attn<<<512, 512, 0, stream>>>(qg, kg, vt, ml, mixg, lnhg, lnhb, dout + 1024, oh);
  k_epi<<<128, 512, 0, stream>>>(oh, woutT, bo, logv, lob, dout);
}